// Round 10
// baseline (137.345 us; speedup 1.0000x reference)
//
#include <hip/hip_runtime.h>
#include <hip/hip_bf16.h>
#include <stdint.h>

#define B_ROWS 4096
#define D_DIM  512
#define N2     8192
#define NBLK2  32                          // 8192 / 256
#define NTRI2  (NBLK2 * (NBLK2 + 1) / 2)   // 528 upper-tri blocks (528 = 8*66)

typedef __attribute__((ext_vector_type(8))) short bf16x8;
typedef __attribute__((ext_vector_type(4))) float f32x4;

#define VMW(n) asm volatile("s_waitcnt vmcnt(" #n ")" ::: "memory")
#define LG0()  asm volatile("s_waitcnt lgkmcnt(0)" ::: "memory")
#define BAR()  __builtin_amdgcn_s_barrier()

// ---------------------------------------------------------------------------
// Kernel 1: row L2-norms, normalize, cast to bf16. Also zeroes denom[row].
// (unchanged from round 2/7 — proven)
// ---------------------------------------------------------------------------
__global__ void normalize_kernel(const float* __restrict__ zi,
                                 const float* __restrict__ zj,
                                 ushort* __restrict__ zn,
                                 float* __restrict__ denom) {
    const int row = blockIdx.x;         // 0..8191
    const int t   = threadIdx.x;        // 256 threads, one float2 each
    if (t == 0) denom[row] = 0.0f;
    const float* src = (row < B_ROWS) ? (zi + (size_t)row * D_DIM)
                                      : (zj + (size_t)(row - B_ROWS) * D_DIM);
    float2 v = ((const float2*)src)[t];
    float ss = v.x * v.x + v.y * v.y;
    #pragma unroll
    for (int off = 1; off < 64; off <<= 1) ss += __shfl_xor(ss, off);
    __shared__ float red[4];
    if ((t & 63) == 0) red[t >> 6] = ss;
    __syncthreads();
    const float tot = red[0] + red[1] + red[2] + red[3];
    const float inv = 1.0f / sqrtf(tot);   // norms ~22.6 >> eps
    __hip_bfloat16 hx = __float2bfloat16(v.x * inv);
    __hip_bfloat16 hy = __float2bfloat16(v.y * inv);
    ushort2 h;
    h.x = *(ushort*)&hx;
    h.y = *(ushort*)&hy;
    ((ushort2*)zn)[(size_t)row * (D_DIM / 2) + t] = h;
}

// ---------------------------------------------------------------------------
// Kernel 2 (round-8 rewrite): 256x256 upper-tri tiles, 8 waves (2Mx4N),
// BK=32, 4-slot LDS ring (128 KB dynamic) with counted-vmcnt depth-3
// prefetch (T3+T4), XOR LDS swizzle (T2, rule #21: linear gload_lds dest +
// inverse-swizzled global source + same XOR on ds_read), setprio around
// MFMA clusters (T5), XCD-chunked bid swizzle (T1). Fused exp / diag-mask /
// positives / row+col sums epilogue as before.
// LDS slot s (32 KB): A[256][32] at s*16384, B[256][32] at s*16384+8192 (ushorts).
// ---------------------------------------------------------------------------
__global__ __launch_bounds__(512, 2) void gram_kernel(const ushort* __restrict__ zn,
                                                      float* __restrict__ denom,
                                                      float* __restrict__ pos) {
    extern __shared__ ushort lds[];   // 4 * 16384 ushorts = 128 KB

    const int tid  = threadIdx.x;     // 0..511
    const int lane = tid & 63;
    const int wave = tid >> 6;        // 0..7
    const int wr   = wave >> 2;       // 0..1  (row half: 128 rows)
    const int wc   = wave & 3;        // 0..3  (col quarter: 64 cols)

    // T1: XCD-chunked bijective swizzle (528 = 8 * 66), then tri-decode
    const int g   = blockIdx.x;
    const int bid = (g & 7) * (NTRI2 / 8) + (g >> 3);
    int by = (int)((sqrtf(8.0f * (float)bid + 1.0f) - 1.0f) * 0.5f);
    while ((by * (by + 1)) / 2 > bid) --by;
    while (((by + 1) * (by + 2)) / 2 <= bid) ++by;
    const int bx = bid - (by * (by + 1)) / 2;
    const int row0 = bx * 256;
    const int col0 = by * 256;
    const bool offdiag = (bx != by);

    // T2 swizzle: LDS cell (row, cb) holds global 16B-block cb ^ (row&3) ^ ((row>>2)&3).
    // Stage (linear dest): thread tid covers rl = (tid>>2) + 128*(q&1), cb = tid&3;
    // source col block pre-swizzled with rl's bits = tid>>2 bits.
    const int csw = (((tid & 3) ^ ((tid >> 2) & 3) ^ ((tid >> 4) & 3)) << 3); // ushorts
    const int srl = (tid >> 2);   // 0..127 row within half

    // Reader's swizzled k-block (lane-constant): rows ≡ (lane&15) mod 16.
    const int kx = ((((lane >> 4) ^ (lane & 3) ^ ((lane >> 2) & 3))) << 3);   // ushorts

    // STG: staging round q (0:A-low,1:A-high,2:B-low,3:B-high) of K-tile kt into slot ts
    #define STG(q, kt, ts)                                                             \
        do {                                                                           \
            const int rl_ = srl + (((q) & 1) << 7);                                    \
            const ushort* src_ = zn + (size_t)((((q) >> 1) ? col0 : row0) + rl_) * D_DIM \
                                 + (kt) * 32 + csw;                                    \
            ushort* dst_ = lds + (ts) * 16384 + (((q) >> 1) << 13) + (((q) & 1) << 12) \
                           + tid * 8;                                                  \
            __builtin_amdgcn_global_load_lds(                                          \
                (const __attribute__((address_space(1))) void*)src_,                   \
                (__attribute__((address_space(3))) void*)dst_, 16, 0, 0);              \
        } while (0)

    f32x4 acc[8][4];
    #pragma unroll
    for (int m = 0; m < 8; ++m)
        #pragma unroll
        for (int n = 0; n < 4; ++n)
            acc[m][n] = (f32x4){0.f, 0.f, 0.f, 0.f};

    bf16x8 af[4], bf[4];

    // A-frag row (within tile) for quadrant qm, sub-row mm: wr*128 + qm*64 + mm*16 + (lane&15)
    const int ar_base = wr * 128 + (lane & 15);
    const int br_base = wc * 64 + (lane & 15);

    #define LDA(mm, qm)                                                                   \
        af[mm] = *(const bf16x8*)(lds + slot * 16384 +                                    \
                                  (size_t)(ar_base + (qm) * 64 + (mm) * 16) * 32 + kx)
    #define LDB(nn)                                                                       \
        bf[nn] = *(const bf16x8*)(lds + slot * 16384 + 8192 +                             \
                                  (size_t)(br_base + (nn) * 16) * 32 + kx)
    #define MFMA8(mbase, n0, n1)                                                          \
        do {                                                                              \
            _Pragma("unroll")                                                             \
            for (int mm_ = 0; mm_ < 4; ++mm_) {                                           \
                acc[(mbase) + mm_][n0] = __builtin_amdgcn_mfma_f32_16x16x32_bf16(         \
                    af[mm_], bf[n0], acc[(mbase) + mm_][n0], 0, 0, 0);                    \
                acc[(mbase) + mm_][n1] = __builtin_amdgcn_mfma_f32_16x16x32_bf16(         \
                    af[mm_], bf[n1], acc[(mbase) + mm_][n1], 0, 0, 0);                    \
            }                                                                             \
        } while (0)

    // ---- prologue: stage K-tiles 0,1,2 into slots 0,1,2 (12 loads/thread) ----
    #pragma unroll
    for (int s = 0; s < 3; ++s) {
        STG(0, s, s); STG(1, s, s); STG(2, s, s); STG(3, s, s);
    }
    VMW(8);   // slot 0 landed (slots 1,2 = 8 loads may remain in flight)
    BAR();

    // ---- main loop: 16 K-steps, 4 phases each ----
    #pragma unroll
    for (int t = 0; t < 16; ++t) {
        const int slot  = t & 3;
        const bool st   = (t <= 12);
        const int nkt   = t + 3;
        const int nslot = nkt & 3;   // != slot (t+3 mod 4), readers of it done at step t-1

        // phase 0: read af(qm0) + bf(n0,n1); stage round 0; MFMA quad (0, n0/n1)
        LDA(0, 0); LDA(1, 0); LDA(2, 0); LDA(3, 0);
        LDB(0); LDB(1);
        if (st) STG(0, nkt, nslot);
        BAR(); LG0();
        __builtin_amdgcn_s_setprio(1);
        MFMA8(0, 0, 1);
        __builtin_amdgcn_s_setprio(0);
        BAR();

        // phase 1: read bf(n2,n3); stage round 1; MFMA quad (0, n2/n3)
        LDB(2); LDB(3);
        if (st) STG(1, nkt, nslot);
        BAR(); LG0();
        __builtin_amdgcn_s_setprio(1);
        MFMA8(0, 2, 3);
        __builtin_amdgcn_s_setprio(0);
        BAR();

        // phase 2: read af(qm1); stage round 2; MFMA quad (4, n2/n3)
        LDA(0, 1); LDA(1, 1); LDA(2, 1); LDA(3, 1);
        if (st) STG(2, nkt, nslot);
        BAR(); LG0();
        __builtin_amdgcn_s_setprio(1);
        MFMA8(4, 2, 3);
        __builtin_amdgcn_s_setprio(0);
        BAR();

        // phase 3: stage round 3; MFMA quad (4, n0/n1); counted guard for slot t+1
        if (st) STG(3, nkt, nslot);
        BAR();
        __builtin_amdgcn_s_setprio(1);
        MFMA8(4, 0, 1);
        __builtin_amdgcn_s_setprio(0);
        if (t <= 12)      VMW(8);   // guard slot t+1: slots t+2,t+3 (8 loads) may fly
        else if (t == 13) VMW(4);   // guard 14: only slot 15 in flight
        else if (t == 14) VMW(0);   // guard 15: nothing newer
        BAR();
    }
    #undef STG
    #undef LDA
    #undef LDB
    #undef MFMA8

    // ---- epilogue: exp / diag-mask / positives / row+col sums ----
    const int colb0 = col0 + wc * 64 + (lane & 15);
    float cs[4] = {0.f, 0.f, 0.f, 0.f};
    #pragma unroll
    for (int m = 0; m < 8; ++m) {
        const int rowb = row0 + wr * 128 + m * 16 + (lane >> 4) * 4;
        float rs[4] = {0.f, 0.f, 0.f, 0.f};
        #pragma unroll
        for (int n = 0; n < 4; ++n) {
            const int gcol = colb0 + n * 16;
            #pragma unroll
            for (int j = 0; j < 4; ++j) {
                const int grow = rowb + j;
                const float s2 = 2.0f * acc[m][n][j];   // sim / T,  T = 0.5
                const float e  = (grow == gcol) ? 0.0f : __expf(s2);
                if (gcol - grow == B_ROWS) {            // +B diagonal (once per pair)
                    pos[grow] = s2;
                    pos[gcol] = s2;
                }
                rs[j] += e;
                cs[n] += e;
            }
        }
        #pragma unroll
        for (int off = 1; off < 16; off <<= 1) {
            rs[0] += __shfl_xor(rs[0], off);
            rs[1] += __shfl_xor(rs[1], off);
            rs[2] += __shfl_xor(rs[2], off);
            rs[3] += __shfl_xor(rs[3], off);
        }
        if ((lane & 15) == 0) {
            atomicAdd(&denom[rowb + 0], rs[0]);
            atomicAdd(&denom[rowb + 1], rs[1]);
            atomicAdd(&denom[rowb + 2], rs[2]);
            atomicAdd(&denom[rowb + 3], rs[3]);
        }
    }
    if (offdiag) {
        #pragma unroll
        for (int off = 16; off < 64; off <<= 1) {
            cs[0] += __shfl_xor(cs[0], off);
            cs[1] += __shfl_xor(cs[1], off);
            cs[2] += __shfl_xor(cs[2], off);
            cs[3] += __shfl_xor(cs[3], off);
        }
        if (lane < 16) {
            atomicAdd(&denom[colb0 + 0],  cs[0]);
            atomicAdd(&denom[colb0 + 16], cs[1]);
            atomicAdd(&denom[colb0 + 32], cs[2]);
            atomicAdd(&denom[colb0 + 48], cs[3]);
        }
    }
}

// ---------------------------------------------------------------------------
// Kernel 3: loss = mean( log(denom + 1e-8) - pos )   (unchanged)
// ---------------------------------------------------------------------------
__global__ void loss_kernel(const float* __restrict__ denom,
                            const float* __restrict__ pos,
                            float* __restrict__ out) {
    const int t = threadIdx.x;      // 1024 threads
    float partial = 0.f;
    for (int i = t; i < N2; i += 1024)
        partial += logf(denom[i] + 1e-8f) - pos[i];
    #pragma unroll
    for (int off = 1; off < 64; off <<= 1) partial += __shfl_xor(partial, off);
    __shared__ float red[16];
    if ((t & 63) == 0) red[t >> 6] = partial;
    __syncthreads();
    if (t == 0) {
        float s = 0.f;
        #pragma unroll
        for (int i = 0; i < 16; ++i) s += red[i];
        out[0] = s * (1.0f / (float)N2);
    }
}

// ---------------------------------------------------------------------------
extern "C" void kernel_launch(void* const* d_in, const int* in_sizes, int n_in,
                              void* d_out, int out_size, void* d_ws, size_t ws_size,
                              hipStream_t stream) {
    const float* zi = (const float*)d_in[0];
    const float* zj = (const float*)d_in[1];
    char* ws = (char*)d_ws;
    ushort* zn   = (ushort*)ws;                              // 8192*512 bf16 = 8 MB
    float* denom = (float*)(ws + (size_t)N2 * D_DIM * 2);    // 8192 f32
    float* pos   = denom + N2;                               // 8192 f32
    float* out   = (float*)d_out;

    // allow 128 KB dynamic LDS (host-side attribute set; not a stream op)
    hipFuncSetAttribute((const void*)gram_kernel,
                        hipFuncAttributeMaxDynamicSharedMemorySize, 131072);

    normalize_kernel<<<N2, 256, 0, stream>>>(zi, zj, zn, denom);
    gram_kernel<<<NTRI2, 512, 131072, stream>>>(zn, denom, pos);
    loss_kernel<<<1, 1024, 0, stream>>>(denom, pos, out);
}